// Round 2
// baseline (12953.189 us; speedup 1.0000x reference)
//
#include <hip/hip_runtime.h>
#include <hip/hip_bf16.h>

#define BB 2
#define SS 512
#define TT (BB*SS)
#define HIDD 256
#define NHH 8
#define HDD 32
#define NLL 12
#define MLPD 1024
#define VDD 384
#define SDD 384
#define TDD 5
#define RDD 64
#define EPSV 1e-5f

// Float inputs may be bf16 or f32 on device (reference is f32; harness policy
// ambiguous). Detected at runtime from ln_g (known all-ones): first u32 is
// 0x3F803F80 (bf16x2) vs 0x3F800000 (f32). Bool width (1/4/8 B) detected from
// mask_full (known all-true). fl[0]=bool esz, fl[1]=1 if f32 else 0.
// Weight slices are passed as (base pointer, element offset) so no host-side
// byte math depends on the unknown element size.

__device__ __forceinline__ float ldf(const void* p, size_t i, int F){
  if (F) return ((const float*)p)[i];
  return __bfloat162float(((const __hip_bfloat16*)p)[i]);
}

__device__ __forceinline__ bool getb(const void* p, long long i, int esz){
  if (esz == 1) return ((const unsigned char*)p)[i] != 0;
  if (esz == 4) return ((const int*)p)[i] != 0;
  return ((const long long*)p)[i] != 0;
}

__global__ void detect_kernel(const void* mask_full, const void* ln_g, int* fl){
  const unsigned int* w = (const unsigned int*)mask_full;
  int esz;
  if (w[0] == 0x01010101u) esz = 1;
  else if (w[0] == 1u && w[1] == 0u) esz = 8;
  else esz = 4;
  fl[0] = esz;
  unsigned int g0 = ((const unsigned int*)ln_g)[0];
  fl[1] = (g0 == 0x3F800000u) ? 1 : 0;
}

__device__ __forceinline__ float block_sum256(float v, float* red){
  #pragma unroll
  for (int off = 32; off; off >>= 1) v += __shfl_down(v, off);
  int w = threadIdx.x >> 6;
  if ((threadIdx.x & 63) == 0) red[w] = v;
  __syncthreads();
  float s = red[0] + red[1] + red[2] + red[3];
  __syncthreads();
  return s;
}

// ---------------- embedding + gate ----------------
__global__ void embed_kernel(const void* ve, const void* se, const void* te, const void* re,
    const void* Wsch, const void* Wtem, const void* Wrol, const void* Edt,
    const void* Wval, const void* Wg, const void* bg, const void* Emsk,
    const int* dtype_ids, const void* is_masked, const void* padmask,
    const int* fl, float* x)
{
  __shared__ float sve[VDD], sse[SDD], ste[TDD], sre[RDD], ctx[5*HIDD];
  int t = blockIdx.x, h = threadIdx.x;
  int esz = fl[0], F = fl[1];
  for (int i = h; i < VDD; i += 256){ sve[i] = ldf(ve, (size_t)t*VDD+i, F); sse[i] = ldf(se, (size_t)t*SDD+i, F); }
  if (h < TDD) ste[h] = ldf(te, (size_t)t*TDD+h, F);
  if (h < RDD) sre[h] = ldf(re, (size_t)t*RDD+h, F);
  __syncthreads();
  int d = dtype_ids[t];
  bool msk = getb(is_masked, t, esz);
  bool pad = getb(padmask, t, esz);
  float vp;
  if (msk) {
    vp = ldf(Emsk, (size_t)d*HIDD + h, F);
  } else {
    float a = 0.f;
    size_t wv = (size_t)d*VDD*HIDD;
    for (int v = 0; v < VDD; v++) a += sve[v]*ldf(Wval, wv + (size_t)v*HIDD + h, F);
    vp = a;
  }
  float sp = 0.f; for (int v = 0; v < SDD; v++) sp += sse[v]*ldf(Wsch, (size_t)v*HIDD + h, F);
  float tp = 0.f; for (int v = 0; v < TDD; v++) tp += ste[v]*ldf(Wtem, (size_t)v*HIDD + h, F);
  float rp = 0.f; for (int v = 0; v < RDD; v++) rp += sre[v]*ldf(Wrol, (size_t)v*HIDD + h, F);
  float de = ldf(Edt, (size_t)d*HIDD + h, F);
  ctx[h] = vp; ctx[HIDD+h] = sp; ctx[2*HIDD+h] = tp; ctx[3*HIDD+h] = rp; ctx[4*HIDD+h] = de;
  __syncthreads();
  float g = 0.f;
  for (int j = 0; j < 5*HIDD; j++) g += ctx[j]*ldf(Wg, (size_t)j*HIDD + h, F);
  g += ldf(bg, h, F);
  g = 1.f/(1.f + __expf(-g));
  float comb = vp + sp + tp + rp + de;
  x[t*HIDD + h] = comb * g * (pad ? 1.f : 0.f);
}

// ---------------- LN + QKV projection ----------------
__global__ void lnqkv_kernel(const float* __restrict__ x, const void* g, const void* bta,
                             size_t goff, const void* qw, size_t woff,
                             const int* fl, float* __restrict__ qkvb)
{
  __shared__ float y[HIDD];
  __shared__ float red[4];
  int t = blockIdx.x, h = threadIdx.x;
  int F = fl[1];
  float xv = x[t*HIDD + h];
  float mean = block_sum256(xv, red) * (1.f/HIDD);
  float dv = xv - mean;
  float var = block_sum256(dv*dv, red) * (1.f/HIDD);
  y[h] = dv * rsqrtf(var + EPSV) * ldf(g, goff + h, F) + ldf(bta, goff + h, F);
  __syncthreads();
  float a0 = 0.f, a1 = 0.f, a2 = 0.f;
  for (int k = 0; k < HIDD; k++){
    float yk = y[k];
    size_t w = woff + (size_t)k*768 + h;
    a0 += yk*ldf(qw, w, F); a1 += yk*ldf(qw, w+256, F); a2 += yk*ldf(qw, w+512, F);
  }
  float* o = qkvb + (size_t)t*768 + h;
  o[0] = a0; o[256] = a1; o[512] = a2;
}

// ---------------- masked attention (one wave per query row) ----------------
__global__ void attn_kernel(const float* __restrict__ qkvb, const void* mask,
                            const void* padmask, const int* fl, float* __restrict__ ob)
{
  int tid = threadIdx.x, lane = tid & 63, w = tid >> 6;
  int r = blockIdx.x*4 + w;            // row id in [0, B*NH*S)
  int b = r >> 12;                     // NH*S = 4096
  int rem = r & 4095;
  int h = rem >> 9;
  int q = rem & 511;
  int esz = fl[0];

  const float* qrow = qkvb + ((size_t)(b*SS + q))*768 + h*HDD;
  float qv[HDD];
  #pragma unroll
  for (int d = 0; d < HDD; d++) qv[d] = qrow[d];
  bool padq = getb(padmask, b*SS + q, esz);

  const long long mrow = ((long long)(b*SS + q))*SS;
  float sc[8]; int mbits = 0;
  float mx = -1e30f;
  for (int i = 0; i < 8; i++){
    int s = i*64 + lane;
    bool me = (s == q);
    if (!me){
      bool mm = getb(mask, mrow + s, esz);
      if (mm && padq && getb(padmask, b*SS + s, esz)) me = true;
    }
    float a = 0.f;
    const float* kr = qkvb + ((size_t)(b*SS + s))*768 + 256 + h*HDD;
    #pragma unroll
    for (int d = 0; d < HDD; d++) a += qv[d]*kr[d];
    a *= 0.17677669529663687f;   // 32^-0.5
    sc[i] = me ? a : -1e30f;
    if (me){ mbits |= 1 << i; if (a > mx) mx = a; }
  }
  #pragma unroll
  for (int off = 1; off < 64; off <<= 1){ float o = __shfl_xor(mx, off); if (o > mx) mx = o; }

  float acc[HDD];
  #pragma unroll
  for (int d = 0; d < HDD; d++) acc[d] = 0.f;
  float sum = 0.f;
  for (int i = 0; i < 8; i++){
    int s = i*64 + lane;
    float p = ((mbits >> i) & 1) ? __expf(sc[i] - mx) : 0.f;
    sum += p;
    if (p != 0.f){
      const float* vr = qkvb + ((size_t)(b*SS + s))*768 + 512 + h*HDD;
      #pragma unroll
      for (int d = 0; d < HDD; d++) acc[d] += p*vr[d];
    }
  }
  #pragma unroll
  for (int off = 1; off < 64; off <<= 1) sum += __shfl_xor(sum, off);
  float inv = (sum > 0.f) ? 1.f/sum : 0.f;

  float* orow = ob + ((size_t)(b*SS + q))*HIDD + h*HDD;
  #pragma unroll
  for (int d = 0; d < HDD; d++){
    float v = acc[d];
    #pragma unroll
    for (int off = 32; off; off >>= 1) v += __shfl_down(v, off);
    if (lane == 0) orow[d] = v*inv;
  }
}

// ---------------- attention out-proj + residual ----------------
__global__ void outproj_kernel(const float* __restrict__ ob, const void* ow, size_t woff,
                               const int* fl, float* __restrict__ x)
{
  __shared__ float orow[HIDD];
  int t = blockIdx.x, h = threadIdx.x;
  int F = fl[1];
  orow[h] = ob[(size_t)t*HIDD + h];
  __syncthreads();
  float a = 0.f;
  for (int c = 0; c < HIDD; c++) a += orow[c]*ldf(ow, woff + (size_t)c*HIDD + h, F);
  x[(size_t)t*HIDD + h] += a;
}

// ---------------- LN + FC1 + SiLU gate ----------------
__global__ void fc1_kernel(const float* __restrict__ x, const void* g, const void* bta, size_t goff,
                           const void* fw, size_t woff, const void* fb, size_t boff,
                           const int* fl, float* __restrict__ mb)
{
  __shared__ float y[HIDD];
  __shared__ float red[4];
  int t = blockIdx.x, h = threadIdx.x;
  int F = fl[1];
  float xv = x[(size_t)t*HIDD + h];
  float mean = block_sum256(xv, red) * (1.f/HIDD);
  float dv = xv - mean;
  float var = block_sum256(dv*dv, red) * (1.f/HIDD);
  y[h] = dv * rsqrtf(var + EPSV) * ldf(g, goff + h, F) + ldf(bta, goff + h, F);
  __syncthreads();
  float acc[8];
  #pragma unroll
  for (int j = 0; j < 8; j++) acc[j] = 0.f;
  for (int k = 0; k < HIDD; k++){
    float yk = y[k];
    size_t w = woff + (size_t)k*2048 + h;
    #pragma unroll
    for (int j = 0; j < 8; j++) acc[j] += yk*ldf(fw, w + j*256, F);
  }
  #pragma unroll
  for (int j = 0; j < 8; j++) acc[j] += ldf(fb, boff + h + j*256, F);
  // j<4 -> gate cols (h+j*256 < 1024); j>=4 -> act cols (split pairs c, c+1024)
  #pragma unroll
  for (int k = 0; k < 4; k++){
    float gg = acc[k];
    float s = gg/(1.f + __expf(-gg));      // silu
    mb[(size_t)t*MLPD + h + k*256] = s*acc[k+4];
  }
}

// ---------------- FC2 + bias + residual ----------------
__global__ void fc2_kernel(const float* __restrict__ mb, const void* fw, size_t woff,
                           const void* fb, size_t boff, const int* fl, float* __restrict__ x)
{
  __shared__ float m[MLPD];
  int t = blockIdx.x, h = threadIdx.x;
  int F = fl[1];
  for (int i = h; i < MLPD; i += 256) m[i] = mb[(size_t)t*MLPD + i];
  __syncthreads();
  float a = 0.f;
  for (int j = 0; j < MLPD; j++) a += m[j]*ldf(fw, woff + (size_t)j*HIDD + h, F);
  x[(size_t)t*HIDD + h] += a + ldf(fb, boff + h, F);
}

// ---------------- final LN -> out (dtype matches detected input dtype) ----------------
__global__ void lnf_kernel(const float* __restrict__ x, const void* g, const void* bta,
                           const int* fl, void* out)
{
  __shared__ float red[4];
  int t = blockIdx.x, h = threadIdx.x;
  int F = fl[1];
  float xv = x[(size_t)t*HIDD + h];
  float mean = block_sum256(xv, red) * (1.f/HIDD);
  float dv = xv - mean;
  float var = block_sum256(dv*dv, red) * (1.f/HIDD);
  float yv = dv * rsqrtf(var + EPSV) * ldf(g, h, F) + ldf(bta, h, F);
  size_t idx = (size_t)t*HIDD + h;
  if (F) ((float*)out)[idx] = yv;
  else   ((__hip_bfloat16*)out)[idx] = __float2bfloat16(yv);
}

extern "C" void kernel_launch(void* const* d_in, const int* in_sizes, int n_in,
                              void* d_out, int out_size, void* d_ws, size_t ws_size,
                              hipStream_t stream)
{
  const void* ve    = d_in[0];
  const void* se    = d_in[1];
  const void* te    = d_in[2];
  const void* re    = d_in[3];
  const void* Wsch  = d_in[4];
  const void* Wtem  = d_in[5];
  const void* Wrol  = d_in[6];
  const void* Edt   = d_in[7];
  const void* Wval  = d_in[8];
  const void* Wg    = d_in[9];
  const void* bg    = d_in[10];
  const void* Emsk  = d_in[11];
  const void* qkv_w = d_in[12];
  const void* out_w = d_in[13];
  const void* ln_g  = d_in[14];
  const void* ln_b  = d_in[15];
  const void* fc1_w = d_in[16];
  const void* fc1_b = d_in[17];
  const void* fc2_w = d_in[18];
  const void* fc2_b = d_in[19];
  const void* lnf_g = d_in[20];
  const void* lnf_b = d_in[21];
  const int* dtype_ids = (const int*)d_in[22];
  const void* masks[5] = { d_in[23], d_in[24], d_in[25], d_in[26], d_in[27] };
  const void* is_masked = d_in[28];
  const void* padmask   = d_in[29];

  int*   fl   = (int*)d_ws;
  float* x    = (float*)d_ws + 16;
  float* qkvb = x + (size_t)TT*HIDD;
  float* ob   = qkvb + (size_t)TT*768;
  float* mb   = ob + (size_t)TT*HIDD;

  detect_kernel<<<1, 1, 0, stream>>>(d_in[27], d_in[14], fl);

  embed_kernel<<<TT, 256, 0, stream>>>(ve, se, te, re, Wsch, Wtem, Wrol, Edt, Wval,
                                       Wg, bg, Emsk, dtype_ids, is_masked, padmask,
                                       fl, x);

  for (int l = 0; l < NLL; l++){
    for (int a = 0; a < 5; a++){
      size_t li = (size_t)(l*6 + a);
      lnqkv_kernel<<<TT, 256, 0, stream>>>(x, ln_g, ln_b, li*HIDD,
                                           qkv_w, ((size_t)(l*5 + a))*HIDD*768, fl, qkvb);
      attn_kernel<<<(BB*NHH*SS)/4, 256, 0, stream>>>(qkvb, masks[a], padmask, fl, ob);
      outproj_kernel<<<TT, 256, 0, stream>>>(ob, out_w, ((size_t)(l*5 + a))*HIDD*HIDD, fl, x);
    }
    size_t li = (size_t)(l*6 + 5);
    fc1_kernel<<<TT, 256, 0, stream>>>(x, ln_g, ln_b, li*HIDD,
                                       fc1_w, (size_t)l*HIDD*2048, fc1_b, (size_t)l*2048, fl, mb);
    fc2_kernel<<<TT, 256, 0, stream>>>(mb, fc2_w, (size_t)l*MLPD*HIDD, fc2_b, (size_t)l*HIDD, fl, x);
  }

  lnf_kernel<<<TT, 256, 0, stream>>>(x, lnf_g, lnf_b, fl, d_out);
}